// Round 1
// baseline (397.691 us; speedup 1.0000x reference)
//
#include <hip/hip_runtime.h>
#include <hip/hip_bf16.h>

typedef __attribute__((ext_vector_type(8))) __bf16 bf16x8;
typedef __attribute__((ext_vector_type(8))) short short8;
typedef __attribute__((ext_vector_type(4))) float f32x4;
typedef __attribute__((ext_vector_type(4))) unsigned short ushort4_t;

__device__ __forceinline__ unsigned short f2bf(float f){
  union { float f; unsigned u; } v; v.f = f;
  unsigned r = v.u + 0x7fffu + ((v.u >> 16) & 1u);
  return (unsigned short)(r >> 16);
}
__device__ __forceinline__ float bf2f(unsigned short h){
  union { unsigned u; float f; } v; v.u = ((unsigned)h) << 16;
  return v.f;
}

// Transpose + convert weights to bf16 in workspace:
//   wst0[n][k] = bf16(W0[k][n])  (128 x 256)
//   wst1[n][k] = bf16(W1[k][n])  (128 x 128)
__global__ void prep_weights(const float* __restrict__ W0, const float* __restrict__ W1,
                             unsigned short* __restrict__ wst0, unsigned short* __restrict__ wst1){
  int idx = blockIdx.x * 256 + threadIdx.x;
  if (idx < 256*128){
    int k = idx >> 7, n = idx & 127;
    wst0[n*256 + k] = f2bf(W0[idx]);
  } else if (idx < 256*128 + 128*128){
    int j = idx - 256*128;
    int k = j >> 7, n = j & 127;
    wst1[n*128 + k] = f2bf(W1[j]);
  }
}

// 64 edges per block, 4 waves; wave w computes cols [32w, 32w+32) of h.
__global__ __launch_bounds__(256, 2) void edge_mlp(
    const float* __restrict__ zu, const float* __restrict__ zm,
    const int* __restrict__ row, const int* __restrict__ col,
    const unsigned short* __restrict__ wst0, const unsigned short* __restrict__ wst1,
    const float* __restrict__ b0, const float* __restrict__ b1,
    const float* __restrict__ W2, const float* __restrict__ b2v,
    float* __restrict__ out, int E)
{
  __shared__ unsigned short zA[64][264];   // gathered z, bf16, pad 256->264
  __shared__ unsigned short h0s[64][136];  // hidden 0, bf16, pad 128->136
  __shared__ unsigned short h1s[64][136];  // hidden 1, bf16

  const int tid = threadIdx.x;
  const int e0 = blockIdx.x * 64;

  { // gather + f32->bf16 convert into LDS: 4 threads per edge, 32 floats each
    const int rl = tid >> 2;
    const int part = tid & 3;
    int e = e0 + rl;
    if (e >= E) e = E - 1;
    const long ru = (long)row[e] * 128;
    const long rm = (long)col[e] * 128;
    const float4* su = (const float4*)(zu + ru) + part * 8;
    const float4* sm = (const float4*)(zm + rm) + part * 8;
    #pragma unroll
    for (int i = 0; i < 8; ++i){
      float4 a = su[i];
      float4 b = sm[i];
      int c0 = part * 32 + i * 4;
      ushort4_t pa, pb;
      pa.x = f2bf(a.x); pa.y = f2bf(a.y); pa.z = f2bf(a.z); pa.w = f2bf(a.w);
      pb.x = f2bf(b.x); pb.y = f2bf(b.y); pb.z = f2bf(b.z); pb.w = f2bf(b.w);
      *(ushort4_t*)&zA[rl][c0] = pa;
      *(ushort4_t*)&zA[rl][128 + c0] = pb;
    }
  }
  __syncthreads();

  const int wv = tid >> 6;
  const int lane = tid & 63;
  const int lr = lane & 15;     // A: row / B: col / C: col
  const int lk = lane >> 4;     // k-chunk (8 elems each); C: row-quad
  const int ncol = wv * 32;

  f32x4 acc[4][2];
  #pragma unroll
  for (int mt = 0; mt < 4; ++mt){ acc[mt][0] = (f32x4)(0.f); acc[mt][1] = (f32x4)(0.f); }

  // ---- layer 0: [64,256] x [256,128] ----
  #pragma unroll
  for (int ks = 0; ks < 8; ++ks){
    bf16x8 bf0 = *(const bf16x8*)(wst0 + (ncol + lr) * 256 + ks * 32 + lk * 8);
    bf16x8 bf1 = *(const bf16x8*)(wst0 + (ncol + 16 + lr) * 256 + ks * 32 + lk * 8);
    #pragma unroll
    for (int mt = 0; mt < 4; ++mt){
      bf16x8 a = __builtin_bit_cast(bf16x8, *(const short8*)&zA[mt * 16 + lr][ks * 32 + lk * 8]);
      acc[mt][0] = __builtin_amdgcn_mfma_f32_16x16x32_bf16(a, bf0, acc[mt][0], 0, 0, 0);
      acc[mt][1] = __builtin_amdgcn_mfma_f32_16x16x32_bf16(a, bf1, acc[mt][1], 0, 0, 0);
    }
  }
  { // bias + relu -> h0s
    float bia0 = b0[ncol + lr], bia1 = b0[ncol + 16 + lr];
    #pragma unroll
    for (int mt = 0; mt < 4; ++mt){
      #pragma unroll
      for (int r = 0; r < 4; ++r){
        float v0 = acc[mt][0][r] + bia0; v0 = v0 > 0.f ? v0 : 0.f;
        float v1 = acc[mt][1][r] + bia1; v1 = v1 > 0.f ? v1 : 0.f;
        int rr = mt * 16 + lk * 4 + r;
        h0s[rr][ncol + lr] = f2bf(v0);
        h0s[rr][ncol + 16 + lr] = f2bf(v1);
      }
    }
  }
  __syncthreads();

  // ---- layer 1: [64,128] x [128,128] ----
  #pragma unroll
  for (int mt = 0; mt < 4; ++mt){ acc[mt][0] = (f32x4)(0.f); acc[mt][1] = (f32x4)(0.f); }
  #pragma unroll
  for (int ks = 0; ks < 4; ++ks){
    bf16x8 bf0 = *(const bf16x8*)(wst1 + (ncol + lr) * 128 + ks * 32 + lk * 8);
    bf16x8 bf1 = *(const bf16x8*)(wst1 + (ncol + 16 + lr) * 128 + ks * 32 + lk * 8);
    #pragma unroll
    for (int mt = 0; mt < 4; ++mt){
      bf16x8 a = __builtin_bit_cast(bf16x8, *(const short8*)&h0s[mt * 16 + lr][ks * 32 + lk * 8]);
      acc[mt][0] = __builtin_amdgcn_mfma_f32_16x16x32_bf16(a, bf0, acc[mt][0], 0, 0, 0);
      acc[mt][1] = __builtin_amdgcn_mfma_f32_16x16x32_bf16(a, bf1, acc[mt][1], 0, 0, 0);
    }
  }
  { // bias + relu -> h1s
    float bia0 = b1[ncol + lr], bia1 = b1[ncol + 16 + lr];
    #pragma unroll
    for (int mt = 0; mt < 4; ++mt){
      #pragma unroll
      for (int r = 0; r < 4; ++r){
        float v0 = acc[mt][0][r] + bia0; v0 = v0 > 0.f ? v0 : 0.f;
        float v1 = acc[mt][1][r] + bia1; v1 = v1 > 0.f ? v1 : 0.f;
        int rr = mt * 16 + lk * 4 + r;
        h1s[rr][ncol + lr] = f2bf(v0);
        h1s[rr][ncol + 16 + lr] = f2bf(v1);
      }
    }
  }
  __syncthreads();

  { // ---- layer 2: out[e] = h1[e,:] . W2 + b2 ---- (4 threads per edge)
    const int el = tid >> 2;
    const int part = tid & 3;
    float s = 0.f;
    const float4* w2v = (const float4*)W2 + part * 8;
    #pragma unroll
    for (int i = 0; i < 4; ++i){
      short8 hv = *(const short8*)&h1s[el][part * 32 + i * 8];
      float4 wa = w2v[i * 2];
      float4 wb = w2v[i * 2 + 1];
      s += bf2f((unsigned short)hv[0]) * wa.x;
      s += bf2f((unsigned short)hv[1]) * wa.y;
      s += bf2f((unsigned short)hv[2]) * wa.z;
      s += bf2f((unsigned short)hv[3]) * wa.w;
      s += bf2f((unsigned short)hv[4]) * wb.x;
      s += bf2f((unsigned short)hv[5]) * wb.y;
      s += bf2f((unsigned short)hv[6]) * wb.z;
      s += bf2f((unsigned short)hv[7]) * wb.w;
    }
    s += __shfl_xor(s, 1);
    s += __shfl_xor(s, 2);
    int e = e0 + el;
    if (part == 0 && e < E) out[e] = s + b2v[0];
  }
}

extern "C" void kernel_launch(void* const* d_in, const int* in_sizes, int n_in,
                              void* d_out, int out_size, void* d_ws, size_t ws_size,
                              hipStream_t stream) {
  const float* zu = (const float*)d_in[0];
  const float* zm = (const float*)d_in[1];
  const int*   row = (const int*)d_in[2];
  const int*   col = (const int*)d_in[3];
  const float* W0 = (const float*)d_in[4];
  const float* b0 = (const float*)d_in[5];
  const float* W1 = (const float*)d_in[6];
  const float* b1 = (const float*)d_in[7];
  const float* W2 = (const float*)d_in[8];
  const float* b2 = (const float*)d_in[9];
  const int E = in_sizes[2];

  unsigned short* wst0 = (unsigned short*)d_ws;              // 128*256 bf16
  unsigned short* wst1 = wst0 + 256 * 128;                   // 128*128 bf16

  hipLaunchKernelGGL(prep_weights, dim3(192), dim3(256), 0, stream, W0, W1, wst0, wst1);

  const int nblk = (E + 63) / 64;
  hipLaunchKernelGGL(edge_mlp, dim3(nblk), dim3(256), 0, stream,
                     zu, zm, row, col, wst0, wst1, b0, b1, W2, b2, (float*)d_out, E);
}

// Round 2
// 350.762 us; speedup vs baseline: 1.1338x; 1.1338x over previous
//
#include <hip/hip_runtime.h>
#include <hip/hip_bf16.h>

typedef __attribute__((ext_vector_type(8))) __bf16 bf16x8;
typedef __attribute__((ext_vector_type(8))) short short8;
typedef __attribute__((ext_vector_type(8))) unsigned short ushort8;
typedef __attribute__((ext_vector_type(4))) float f32x4;

__device__ __forceinline__ unsigned short f2bf(float f){
  union { float f; unsigned u; } v; v.f = f;
  unsigned r = v.u + 0x7fffu + ((v.u >> 16) & 1u);
  return (unsigned short)(r >> 16);
}
__device__ __forceinline__ float bf2f(unsigned short h){
  union { unsigned u; float f; } v; v.u = ((unsigned)h) << 16;
  return v.f;
}

// Transpose + convert weights to bf16 in workspace:
//   wst0[n][k] = bf16(W0[k][n])  (128 x 256)
//   wst1[n][k] = bf16(W1[k][n])  (128 x 128)
__global__ void prep_weights(const float* __restrict__ W0, const float* __restrict__ W1,
                             unsigned short* __restrict__ wst0, unsigned short* __restrict__ wst1){
  int idx = blockIdx.x * 256 + threadIdx.x;
  if (idx < 256*128){
    int k = idx >> 7, n = idx & 127;
    wst0[n*256 + k] = f2bf(W0[idx]);
  } else if (idx < 256*128 + 128*128){
    int j = idx - 256*128;
    int k = j >> 7, n = j & 127;
    wst1[n*128 + k] = f2bf(W1[j]);
  }
}

// 64 edges per block, 4 waves; wave w computes cols [32w, 32w+32) of h.
// Single 32 KB LDS arena, time-shared:
//   phase 0 (gather+layer0):  zA  = 64 rows x 512 B (256 bf16), XOR-swizzled
//   phase 1 (layer1 input):   h0  = bytes [0, 16384), 64 rows x 256 B
//   phase 2 (layer2 input):   h1  = bytes [16384, 32768), 64 rows x 256 B
// Swizzle (both write & read sides): byte ^= ((row & 7) << 4)
__global__ __launch_bounds__(256, 4) void edge_mlp(
    const float* __restrict__ zu, const float* __restrict__ zm,
    const int* __restrict__ row, const int* __restrict__ col,
    const unsigned short* __restrict__ wst0, const unsigned short* __restrict__ wst1,
    const float* __restrict__ b0, const float* __restrict__ b1,
    const float* __restrict__ W2, const float* __restrict__ b2v,
    float* __restrict__ out, int E)
{
  __shared__ unsigned char smem[32768];

  const int tid = threadIdx.x;
  const int e0 = blockIdx.x * 64;

  { // gather + f32->bf16 convert into swizzled zA
    const int rl = tid >> 2;          // 0..63: edge slot
    const int part = tid & 3;         // 0..3: 256-B slice (0,1=user / 2,3=movie)
    int e = e0 + rl;
    if (e >= E) e = E - 1;
    const float* src;
    if (part < 2) src = zu + (long)row[e] * 128 + part * 64;
    else          src = zm + (long)col[e] * 128 + (part - 2) * 64;
    const float4* s4 = (const float4*)src;
    const unsigned xr = (unsigned)((rl & 7) << 4);
    #pragma unroll
    for (int j = 0; j < 8; ++j){
      float4 a = s4[j * 2];
      float4 b = s4[j * 2 + 1];
      ushort8 p;
      p[0] = f2bf(a.x); p[1] = f2bf(a.y); p[2] = f2bf(a.z); p[3] = f2bf(a.w);
      p[4] = f2bf(b.x); p[5] = f2bf(b.y); p[6] = f2bf(b.z); p[7] = f2bf(b.w);
      int chunk = part * 8 + j;                       // 0..31 16-B chunks per row
      *(ushort8*)&smem[rl * 512 + ((chunk * 16) ^ xr)] = p;
    }
  }
  __syncthreads();

  const int wv = tid >> 6;
  const int lane = tid & 63;
  const int lr = lane & 15;     // A: row-in-16 / B,C: col
  const int lk = lane >> 4;     // k-chunk (8 elems); C: row-quad
  const int ncol = wv * 32;
  const unsigned xl = (unsigned)((lr & 7) << 4);   // swizzle for A-frag reads

  f32x4 acc[4][2];
  #pragma unroll
  for (int mt = 0; mt < 4; ++mt){ acc[mt][0] = (f32x4)(0.f); acc[mt][1] = (f32x4)(0.f); }

  // ---- layer 0: [64,256] x [256,128] ----
  #pragma unroll
  for (int ks = 0; ks < 8; ++ks){
    bf16x8 bf0 = *(const bf16x8*)(wst0 + (ncol + lr) * 256 + ks * 32 + lk * 8);
    bf16x8 bf1 = *(const bf16x8*)(wst0 + (ncol + 16 + lr) * 256 + ks * 32 + lk * 8);
    const unsigned cb = (unsigned)((ks * 32 + lk * 8) * 2);
    #pragma unroll
    for (int mt = 0; mt < 4; ++mt){
      bf16x8 a = __builtin_bit_cast(bf16x8,
          *(const short8*)&smem[(mt * 16 + lr) * 512 + (cb ^ xl)]);
      acc[mt][0] = __builtin_amdgcn_mfma_f32_16x16x32_bf16(a, bf0, acc[mt][0], 0, 0, 0);
      acc[mt][1] = __builtin_amdgcn_mfma_f32_16x16x32_bf16(a, bf1, acc[mt][1], 0, 0, 0);
    }
  }
  __syncthreads();   // all waves done reading zA before h0 overwrites the arena

  { // bias + relu -> h0 (arena bytes [0,16384))
    float bia0 = b0[ncol + lr], bia1 = b0[ncol + 16 + lr];
    #pragma unroll
    for (int mt = 0; mt < 4; ++mt){
      #pragma unroll
      for (int r = 0; r < 4; ++r){
        float v0 = acc[mt][0][r] + bia0; v0 = v0 > 0.f ? v0 : 0.f;
        float v1 = acc[mt][1][r] + bia1; v1 = v1 > 0.f ? v1 : 0.f;
        int rr = mt * 16 + lk * 4 + r;
        unsigned xw = (unsigned)((rr & 7) << 4);
        *(unsigned short*)&smem[rr * 256 + ((unsigned)((ncol + lr) * 2) ^ xw)] = f2bf(v0);
        *(unsigned short*)&smem[rr * 256 + ((unsigned)((ncol + 16 + lr) * 2) ^ xw)] = f2bf(v1);
      }
    }
  }
  __syncthreads();

  // ---- layer 1: [64,128] x [128,128] ----
  #pragma unroll
  for (int mt = 0; mt < 4; ++mt){ acc[mt][0] = (f32x4)(0.f); acc[mt][1] = (f32x4)(0.f); }
  #pragma unroll
  for (int ks = 0; ks < 4; ++ks){
    bf16x8 bf0 = *(const bf16x8*)(wst1 + (ncol + lr) * 128 + ks * 32 + lk * 8);
    bf16x8 bf1 = *(const bf16x8*)(wst1 + (ncol + 16 + lr) * 128 + ks * 32 + lk * 8);
    const unsigned cb = (unsigned)((ks * 32 + lk * 8) * 2);
    #pragma unroll
    for (int mt = 0; mt < 4; ++mt){
      bf16x8 a = __builtin_bit_cast(bf16x8,
          *(const short8*)&smem[(mt * 16 + lr) * 256 + (cb ^ xl)]);
      acc[mt][0] = __builtin_amdgcn_mfma_f32_16x16x32_bf16(a, bf0, acc[mt][0], 0, 0, 0);
      acc[mt][1] = __builtin_amdgcn_mfma_f32_16x16x32_bf16(a, bf1, acc[mt][1], 0, 0, 0);
    }
  }
  { // bias + relu -> h1 (arena bytes [16384,32768), disjoint from h0: no barrier needed before writes)
    float bia0 = b1[ncol + lr], bia1 = b1[ncol + 16 + lr];
    #pragma unroll
    for (int mt = 0; mt < 4; ++mt){
      #pragma unroll
      for (int r = 0; r < 4; ++r){
        float v0 = acc[mt][0][r] + bia0; v0 = v0 > 0.f ? v0 : 0.f;
        float v1 = acc[mt][1][r] + bia1; v1 = v1 > 0.f ? v1 : 0.f;
        int rr = mt * 16 + lk * 4 + r;
        unsigned xw = (unsigned)((rr & 7) << 4);
        *(unsigned short*)&smem[16384 + rr * 256 + ((unsigned)((ncol + lr) * 2) ^ xw)] = f2bf(v0);
        *(unsigned short*)&smem[16384 + rr * 256 + ((unsigned)((ncol + 16 + lr) * 2) ^ xw)] = f2bf(v1);
      }
    }
  }
  __syncthreads();

  { // ---- layer 2: out[e] = h1[e,:] . W2 + b2 ---- (4 threads per edge)
    const int el = tid >> 2;
    const int part = tid & 3;
    const unsigned xe = (unsigned)((el & 7) << 4);
    float s = 0.f;
    const float4* w2v = (const float4*)W2 + part * 8;
    #pragma unroll
    for (int i = 0; i < 4; ++i){
      short8 hv = *(const short8*)&smem[16384 + el * 256 + ((unsigned)((part * 32 + i * 8) * 2) ^ xe)];
      float4 wa = w2v[i * 2];
      float4 wb = w2v[i * 2 + 1];
      s += bf2f((unsigned short)hv[0]) * wa.x;
      s += bf2f((unsigned short)hv[1]) * wa.y;
      s += bf2f((unsigned short)hv[2]) * wa.z;
      s += bf2f((unsigned short)hv[3]) * wa.w;
      s += bf2f((unsigned short)hv[4]) * wb.x;
      s += bf2f((unsigned short)hv[5]) * wb.y;
      s += bf2f((unsigned short)hv[6]) * wb.z;
      s += bf2f((unsigned short)hv[7]) * wb.w;
    }
    s += __shfl_xor(s, 1);
    s += __shfl_xor(s, 2);
    int e = e0 + el;
    if (part == 0 && e < E) out[e] = s + b2v[0];
  }
}

extern "C" void kernel_launch(void* const* d_in, const int* in_sizes, int n_in,
                              void* d_out, int out_size, void* d_ws, size_t ws_size,
                              hipStream_t stream) {
  const float* zu = (const float*)d_in[0];
  const float* zm = (const float*)d_in[1];
  const int*   row = (const int*)d_in[2];
  const int*   col = (const int*)d_in[3];
  const float* W0 = (const float*)d_in[4];
  const float* b0 = (const float*)d_in[5];
  const float* W1 = (const float*)d_in[6];
  const float* b1 = (const float*)d_in[7];
  const float* W2 = (const float*)d_in[8];
  const float* b2 = (const float*)d_in[9];
  const int E = in_sizes[2];

  unsigned short* wst0 = (unsigned short*)d_ws;              // 128*256 bf16
  unsigned short* wst1 = wst0 + 256 * 128;                   // 128*128 bf16

  hipLaunchKernelGGL(prep_weights, dim3(192), dim3(256), 0, stream, W0, W1, wst0, wst1);

  const int nblk = (E + 63) / 64;
  hipLaunchKernelGGL(edge_mlp, dim3(nblk), dim3(256), 0, stream,
                     zu, zm, row, col, wst0, wst1, b0, b1, W2, b2, (float*)d_out, E);
}

// Round 3
// 263.134 us; speedup vs baseline: 1.5114x; 1.3330x over previous
//
#include <hip/hip_runtime.h>
#include <hip/hip_bf16.h>

typedef __attribute__((ext_vector_type(8))) __bf16 bf16x8;
typedef __attribute__((ext_vector_type(8))) short short8;
typedef __attribute__((ext_vector_type(8))) unsigned short ushort8;
typedef __attribute__((ext_vector_type(4))) unsigned short ushort4v;
typedef __attribute__((ext_vector_type(4))) float f32x4;

__device__ __forceinline__ unsigned short f2bf(float f){
  union { float f; unsigned u; } v; v.f = f;
  unsigned r = v.u + 0x7fffu + ((v.u >> 16) & 1u);
  return (unsigned short)(r >> 16);
}
__device__ __forceinline__ float bf2f(unsigned short h){
  union { unsigned u; float f; } v; v.u = ((unsigned)h) << 16;
  return v.f;
}

// wst0[n][k] = bf16(W0[k][n]) (128x256); wst1[n][k] = bf16(W1[k][n]) (128x128)
__global__ void prep_weights(const float* __restrict__ W0, const float* __restrict__ W1,
                             unsigned short* __restrict__ wst0, unsigned short* __restrict__ wst1){
  int idx = blockIdx.x * 256 + threadIdx.x;
  if (idx < 256*128){
    int k = idx >> 7, n = idx & 127;
    wst0[n*256 + k] = f2bf(W0[idx]);
  } else if (idx < 256*128 + 128*128){
    int j = idx - 256*128;
    int k = j >> 7, n = j & 127;
    wst1[n*128 + k] = f2bf(W1[j]);
  }
}

// f32 -> bf16 table conversion, 8 elems/thread
__global__ void conv_bf16(const float* __restrict__ src, unsigned short* __restrict__ dst, int n8){
  int i = blockIdx.x * 256 + threadIdx.x;
  if (i < n8){
    const float4* s = (const float4*)src + (size_t)i * 2;
    float4 a = s[0], b = s[1];
    ushort8 p;
    p[0]=f2bf(a.x); p[1]=f2bf(a.y); p[2]=f2bf(a.z); p[3]=f2bf(a.w);
    p[4]=f2bf(b.x); p[5]=f2bf(b.y); p[6]=f2bf(b.z); p[7]=f2bf(b.w);
    *(ushort8*)(dst + (size_t)i * 8) = p;
  }
}

// Persistent-block edge MLP. 64 edges/tile, 4 waves; wave w owns out cols [32w,32w+32).
// LDS arena [0,32768): zA (64 rows x 512B, XOR-swizzled) -> reused as h0 [0,16K) + h1 [16K,32K).
// W2 staged at [32768, 33280), chunk j at pos j^(j>>3).
// Row swizzle: byte-in-row ^= ((row&7)<<4), applied on gather source (TAB16) or ds_write (f32).
template<bool TAB16>
__global__ __launch_bounds__(256, 3) void edge_mlp(
    const float* __restrict__ zu, const float* __restrict__ zm,
    const unsigned short* __restrict__ zub, const unsigned short* __restrict__ zmb,
    const int* __restrict__ row, const int* __restrict__ col,
    const unsigned short* __restrict__ wst0, const unsigned short* __restrict__ wst1,
    const float* __restrict__ b0, const float* __restrict__ b1,
    const float* __restrict__ W2, const float* __restrict__ b2v,
    float* __restrict__ out, int E, int ntiles)
{
  __shared__ unsigned char smem[33280];

  const int tid = threadIdx.x;
  const int wv = tid >> 6;
  const int lane = tid & 63;
  const int lr = lane & 15;
  const int lk = lane >> 4;
  const int ncol = wv * 32;
  const unsigned xl = (unsigned)((lr & 7) << 4);

  if (tid < 32){  // stage W2 (512B) swizzled
    float4 wj = ((const float4*)W2)[tid];
    *(float4*)&smem[32768 + (((unsigned)(tid ^ (tid >> 3))) << 4)] = wj;
  }

  const float b00 = b0[ncol + lr], b01 = b0[ncol + 16 + lr];
  const float b10 = b1[ncol + lr], b11 = b1[ncol + 16 + lr];
  const float b2s = b2v[0];

  // persistent weight registers: 64 + 32 VGPRs
  bf16x8 w0r[8][2], w1r[4][2];
  #pragma unroll
  for (int ks = 0; ks < 8; ++ks){
    w0r[ks][0] = *(const bf16x8*)(wst0 + (ncol + lr) * 256 + ks * 32 + lk * 8);
    w0r[ks][1] = *(const bf16x8*)(wst0 + (ncol + 16 + lr) * 256 + ks * 32 + lk * 8);
  }
  #pragma unroll
  for (int ks = 0; ks < 4; ++ks){
    w1r[ks][0] = *(const bf16x8*)(wst1 + (ncol + lr) * 128 + ks * 32 + lk * 8);
    w1r[ks][1] = *(const bf16x8*)(wst1 + (ncol + 16 + lr) * 128 + ks * 32 + lk * 8);
  }

  const int u = lane >> 4;   // unit within wave-pass
  const int c = lane & 15;   // 16B chunk within 256B half-row

  for (int t = blockIdx.x; t < ntiles; t += gridDim.x){
    const int e0 = t * 64;

    // ---- gather 64 edges (user 256B + movie 256B each, bf16) into swizzled zA ----
    int idxs[8];
    #pragma unroll
    for (int p = 0; p < 8; ++p){
      int U = p * 16 + wv * 4 + u;         // unit 0..127: edge = U>>1, half = U&1
      int e = e0 + (U >> 1); if (e >= E) e = E - 1;
      idxs[p] = (U & 1) ? col[e] : row[e];
    }
    if constexpr (TAB16){
      #pragma unroll
      for (int p = 0; p < 8; ++p){
        int U = p * 16 + wv * 4 + u;
        int rl = U >> 1, half = U & 1;
        const unsigned short* src = (half ? zmb : zub)
            + (size_t)idxs[p] * 128 + ((c ^ (rl & 7)) * 8);  // source-side swizzle
        __builtin_amdgcn_global_load_lds(
            (const __attribute__((address_space(1))) unsigned int*)src,
            (__attribute__((address_space(3))) unsigned int*)(smem + (p * 16 + wv * 4) * 256),
            16, 0, 0);
      }
    } else {
      #pragma unroll
      for (int p = 0; p < 8; ++p){
        int U = p * 16 + wv * 4 + u;
        int rl = U >> 1, half = U & 1;
        const float4* s4 = (const float4*)(half ? zm : zu) + (size_t)idxs[p] * 32;
        float4 va = s4[c], vb = s4[c + 16];
        ushort4v pa, pb;
        pa.x=f2bf(va.x); pa.y=f2bf(va.y); pa.z=f2bf(va.z); pa.w=f2bf(va.w);
        pb.x=f2bf(vb.x); pb.y=f2bf(vb.y); pb.z=f2bf(vb.z); pb.w=f2bf(vb.w);
        unsigned base = (unsigned)(rl * 512 + half * 256) + (unsigned)((c & 1) * 8);
        unsigned s0 = ((unsigned)((c >> 1) ^ (rl & 7))) << 4;
        unsigned s1 = ((unsigned)((8 + (c >> 1)) ^ (rl & 7))) << 4;
        *(ushort4v*)&smem[base + s0] = pa;
        *(ushort4v*)&smem[base + s1] = pb;
      }
    }
    __syncthreads();

    // ---- layer 0: zA[64,256] x W0 -> acc ----
    f32x4 acc[4][2];
    #pragma unroll
    for (int mt = 0; mt < 4; ++mt){ acc[mt][0] = (f32x4)(0.f); acc[mt][1] = (f32x4)(0.f); }
    #pragma unroll
    for (int ks = 0; ks < 8; ++ks){
      const unsigned cb = (unsigned)(ks * 64 + lk * 16);
      #pragma unroll
      for (int mt = 0; mt < 4; ++mt){
        bf16x8 a = __builtin_bit_cast(bf16x8,
            *(const short8*)&smem[(mt * 16 + lr) * 512 + (cb ^ xl)]);
        acc[mt][0] = __builtin_amdgcn_mfma_f32_16x16x32_bf16(a, w0r[ks][0], acc[mt][0], 0, 0, 0);
        acc[mt][1] = __builtin_amdgcn_mfma_f32_16x16x32_bf16(a, w0r[ks][1], acc[mt][1], 0, 0, 0);
      }
    }
    __syncthreads();   // zA reads done; arena reusable

    // bias+relu -> h0 at [0,16384)
    #pragma unroll
    for (int mt = 0; mt < 4; ++mt){
      #pragma unroll
      for (int r = 0; r < 4; ++r){
        float v0 = acc[mt][0][r] + b00; v0 = v0 > 0.f ? v0 : 0.f;
        float v1 = acc[mt][1][r] + b01; v1 = v1 > 0.f ? v1 : 0.f;
        int rr = mt * 16 + lk * 4 + r;
        unsigned xw = (unsigned)((rr & 7) << 4);
        *(unsigned short*)&smem[rr * 256 + (((unsigned)((ncol + lr) * 2)) ^ xw)] = f2bf(v0);
        *(unsigned short*)&smem[rr * 256 + (((unsigned)((ncol + 16 + lr) * 2)) ^ xw)] = f2bf(v1);
      }
    }
    __syncthreads();

    // ---- layer 1: h0[64,128] x W1 -> acc ----
    #pragma unroll
    for (int mt = 0; mt < 4; ++mt){ acc[mt][0] = (f32x4)(0.f); acc[mt][1] = (f32x4)(0.f); }
    #pragma unroll
    for (int ks = 0; ks < 4; ++ks){
      const unsigned cb = (unsigned)(ks * 64 + lk * 16);
      #pragma unroll
      for (int mt = 0; mt < 4; ++mt){
        bf16x8 a = __builtin_bit_cast(bf16x8,
            *(const short8*)&smem[(mt * 16 + lr) * 256 + (cb ^ xl)]);
        acc[mt][0] = __builtin_amdgcn_mfma_f32_16x16x32_bf16(a, w1r[ks][0], acc[mt][0], 0, 0, 0);
        acc[mt][1] = __builtin_amdgcn_mfma_f32_16x16x32_bf16(a, w1r[ks][1], acc[mt][1], 0, 0, 0);
      }
    }
    // bias+relu -> h1 at [16384,32768) (disjoint from h0 reads)
    #pragma unroll
    for (int mt = 0; mt < 4; ++mt){
      #pragma unroll
      for (int r = 0; r < 4; ++r){
        float v0 = acc[mt][0][r] + b10; v0 = v0 > 0.f ? v0 : 0.f;
        float v1 = acc[mt][1][r] + b11; v1 = v1 > 0.f ? v1 : 0.f;
        int rr = mt * 16 + lk * 4 + r;
        unsigned xw = (unsigned)((rr & 7) << 4);
        *(unsigned short*)&smem[16384 + rr * 256 + (((unsigned)((ncol + lr) * 2)) ^ xw)] = f2bf(v0);
        *(unsigned short*)&smem[16384 + rr * 256 + (((unsigned)((ncol + 16 + lr) * 2)) ^ xw)] = f2bf(v1);
      }
    }
    __syncthreads();

    // ---- layer 2: out = h1 . W2 + b2 (4 threads/edge) ----
    {
      const int el = tid >> 2, part = tid & 3;
      const unsigned xe = (unsigned)((el & 7) << 4);
      float s = 0.f;
      #pragma unroll
      for (int i = 0; i < 4; ++i){
        short8 hv = *(const short8*)&smem[16384 + el * 256 + (((unsigned)(part * 64 + i * 16)) ^ xe)];
        float4 wa = *(const float4*)&smem[32768 + (((unsigned)((part * 8 + i * 2) ^ part)) << 4)];
        float4 wb = *(const float4*)&smem[32768 + (((unsigned)((part * 8 + i * 2 + 1) ^ part)) << 4)];
        s += bf2f((unsigned short)hv[0]) * wa.x;
        s += bf2f((unsigned short)hv[1]) * wa.y;
        s += bf2f((unsigned short)hv[2]) * wa.z;
        s += bf2f((unsigned short)hv[3]) * wa.w;
        s += bf2f((unsigned short)hv[4]) * wb.x;
        s += bf2f((unsigned short)hv[5]) * wb.y;
        s += bf2f((unsigned short)hv[6]) * wb.z;
        s += bf2f((unsigned short)hv[7]) * wb.w;
      }
      s += __shfl_xor(s, 1);
      s += __shfl_xor(s, 2);
      int e = e0 + el;
      if (part == 0 && e < E) out[e] = s + b2s;
    }
    __syncthreads();   // arena free for next tile's gather
  }
}

extern "C" void kernel_launch(void* const* d_in, const int* in_sizes, int n_in,
                              void* d_out, int out_size, void* d_ws, size_t ws_size,
                              hipStream_t stream) {
  const float* zu = (const float*)d_in[0];
  const float* zm = (const float*)d_in[1];
  const int*   row = (const int*)d_in[2];
  const int*   col = (const int*)d_in[3];
  const float* W0 = (const float*)d_in[4];
  const float* b0 = (const float*)d_in[5];
  const float* W1 = (const float*)d_in[6];
  const float* b1 = (const float*)d_in[7];
  const float* W2 = (const float*)d_in[8];
  const float* b2 = (const float*)d_in[9];
  const int E = in_sizes[2];

  unsigned short* wst0 = (unsigned short*)d_ws;                       // 64 KB
  unsigned short* wst1 = wst0 + 256 * 128;                            // 32 KB
  const size_t nu = (size_t)in_sizes[0];                              // z_user elems
  const size_t nm = (size_t)in_sizes[1];                              // z_movie elems
  unsigned short* zub = (unsigned short*)((char*)d_ws + 98304);
  unsigned short* zmb = zub + nu;
  const bool tab16 = ws_size >= 98304 + (nu + nm) * 2;

  hipLaunchKernelGGL(prep_weights, dim3(192), dim3(256), 0, stream, W0, W1, wst0, wst1);

  const int ntiles = (E + 63) / 64;
  const int grid = ntiles < 768 ? ntiles : 768;

  if (tab16){
    int n8u = (int)(nu / 8), n8m = (int)(nm / 8);
    hipLaunchKernelGGL(conv_bf16, dim3((n8u + 255) / 256), dim3(256), 0, stream, zu, zub, n8u);
    hipLaunchKernelGGL(conv_bf16, dim3((n8m + 255) / 256), dim3(256), 0, stream, zm, zmb, n8m);
    hipLaunchKernelGGL((edge_mlp<true>), dim3(grid), dim3(256), 0, stream,
                       zu, zm, zub, zmb, row, col, wst0, wst1, b0, b1, W2, b2,
                       (float*)d_out, E, ntiles);
  } else {
    hipLaunchKernelGGL((edge_mlp<false>), dim3(grid), dim3(256), 0, stream,
                       zu, zm, zub, zmb, row, col, wst0, wst1, b0, b1, W2, b2,
                       (float*)d_out, E, ntiles);
  }
}